// Round 1
// baseline (445.834 us; speedup 1.0000x reference)
//
#include <hip/hip_runtime.h>

#define N_NODES 100000
#define N_EDGES 1250000
#define D 64

// ---------------------------------------------------------------------------
// Phase 1: scatter-add neighbor features + degree count.
// 64 threads per edge (one per feature). Coalesced 256B read of x[src],
// 64 fp32 atomics into agg[dst], 1 int atomic for degree.
// ---------------------------------------------------------------------------
__global__ void __launch_bounds__(256) sage_scatter(
    const float* __restrict__ x,
    const int* __restrict__ ei,          // [2][N_EDGES] int32
    float* __restrict__ agg,             // = d_out, accumulated in place
    unsigned int* __restrict__ deg) {
    int idx = blockIdx.x * 256 + threadIdx.x;
    int e = idx >> 6;
    int lane = idx & 63;
    if (e >= N_EDGES) return;
    int src = ei[e];
    int dst = ei[N_EDGES + e];
    float v = x[(long long)src * D + lane];
    atomicAdd(&agg[(long long)dst * D + lane], v);
    if (lane == 0) atomicAdd(&deg[dst], 1u);
}

// ---------------------------------------------------------------------------
// Phase 2: out[n] = (agg[n]/max(deg,1)) @ Wn^T + x[n] @ Ws^T + b  (in place).
// Weights in LDS transposed to [k][d] (bank = d%32 -> free 2-way conflict).
// 4 nodes per 256-thread block, grid-stride over node groups.
// ---------------------------------------------------------------------------
__global__ void __launch_bounds__(256) sage_transform(
    const float* __restrict__ x,
    const float* __restrict__ wn,        // [64][64]  (out, in)
    const float* __restrict__ ws,        // [64][64]
    const float* __restrict__ b,
    const unsigned int* __restrict__ deg,
    float* __restrict__ agg_out) {       // = d_out, read agg, write result
    __shared__ float lwn[D * D];
    __shared__ float lws[D * D];
    __shared__ float lag[4][D];
    __shared__ float lx[4][D];

    int tid = threadIdx.x;
    // Coalesced global read, transposed LDS write (one-time).
    for (int i = tid; i < D * D; i += 256) {
        int dd = i >> 6, kk = i & 63;
        lwn[kk * D + dd] = wn[i];
        lws[kk * D + dd] = ws[i];
    }
    int nsub = tid >> 6;       // node within group (0..3)
    int d = tid & 63;          // output feature
    float bv = b[d];

    const int ngroups = N_NODES / 4;   // 25000 exactly
    for (int g = blockIdx.x; g < ngroups; g += gridDim.x) {
        int node = g * 4 + nsub;
        __syncthreads();  // prev-iter compute done before re-staging; also covers weight load on iter 0
        float degf = (float)max(deg[node], 1u);
        lag[nsub][d] = agg_out[(long long)node * D + d] / degf;
        lx[nsub][d] = x[(long long)node * D + d];
        __syncthreads();
        float acc = bv;
        const float* ar = lag[nsub];
        const float* xr = lx[nsub];
#pragma unroll 16
        for (int k = 0; k < D; ++k) {
            acc += ar[k] * lwn[k * D + d] + xr[k] * lws[k * D + d];
        }
        agg_out[(long long)node * D + d] = acc;
    }
}

extern "C" void kernel_launch(void* const* d_in, const int* in_sizes, int n_in,
                              void* d_out, int out_size, void* d_ws, size_t ws_size,
                              hipStream_t stream) {
    const float* x = (const float*)d_in[0];
    const int* ei = (const int*)d_in[1];
    const float* wn = (const float*)d_in[2];
    const float* ws = (const float*)d_in[3];
    const float* b = (const float*)d_in[4];
    float* out = (float*)d_out;
    unsigned int* deg = (unsigned int*)d_ws;

    // Zero the accumulator (d_out) and degree counters (d_ws) every call.
    hipMemsetAsync(d_out, 0, (size_t)N_NODES * D * sizeof(float), stream);
    hipMemsetAsync(d_ws, 0, (size_t)N_NODES * sizeof(unsigned int), stream);

    // Scatter: 64 threads/edge.
    {
        long long total = (long long)N_EDGES * 64;
        int grid = (int)((total + 255) / 256);
        sage_scatter<<<grid, 256, 0, stream>>>(x, ei, out, deg);
    }
    // Transform (in place on d_out).
    sage_transform<<<2048, 256, 0, stream>>>(x, wn, ws, b, deg, out);
}